// Round 15
// baseline (514.636 us; speedup 1.0000x reference)
//
#include <hip/hip_runtime.h>
#include <math.h>

#define D 128
#define WAVES 4                    // waves per block; block covers 128 sources
#define BIAS 16.0f
#define TILEB 8192                 // 32-row A-tile bytes
#define BUFB  8448                 // tile + 256B tshl slot
#define REFK 10

typedef __attribute__((ext_vector_type(8))) short short8;    // 8 bf16
typedef __attribute__((ext_vector_type(16))) float f32x16;   // 32x32 acc

union U8 { short8 s; unsigned u[4]; };

// fp32 -> bf16 bits, round-to-nearest-even
static __device__ __forceinline__ unsigned short f2bf(float x) {
    unsigned u = __float_as_uint(x);
    unsigned r = u + 0x7FFFu + ((u >> 16) & 1u);
    return (unsigned short)(r >> 16);
}

static __device__ __forceinline__ unsigned med3u(unsigned a, unsigned b, unsigned c) {
    unsigned d;
    asm("v_med3_u32 %0, %1, %2, %3" : "=v"(d) : "v"(a), "v"(b), "v"(c));
    return d;
}

// exact sorted-ascending top-5 insert: 4 med3 + 1 min (validated r6-r14)
static __device__ __forceinline__ void ins5(unsigned st[5], unsigned k) {
    st[4] = med3u(st[4], st[3], k);
    st[3] = med3u(st[3], st[2], k);
    st[2] = med3u(st[2], st[1], k);
    st[1] = med3u(st[1], st[0], k);
    st[0] = st[0] < k ? st[0] : k;
}

// exact sorted-ascending top-10 insert: 9 med3 + 1 min (validated r9-r14)
static __device__ __forceinline__ void ins10(unsigned st[REFK], unsigned k) {
    #pragma unroll
    for (int s = REFK - 1; s >= 1; --s) st[s] = med3u(st[s], st[s - 1], k);
    st[0] = st[0] < k ? st[0] : k;
}

static __device__ __forceinline__ void gload_lds16(const void* g, void* l) {
    __builtin_amdgcn_global_load_lds(
        (const __attribute__((address_space(1))) unsigned*)g,
        (__attribute__((address_space(3))) unsigned*)l, 16, 0, 0);
}
static __device__ __forceinline__ void gload_lds4(const void* g, void* l) {
    __builtin_amdgcn_global_load_lds(
        (const __attribute__((address_space(1))) unsigned*)g,
        (__attribute__((address_space(3))) unsigned*)l, 4, 0, 0);
}

// Phase 0: tbf = bf16(-2*tgt), PRE-SWIZZLED (16B-unit u of row r at u^(r&15));
// pad rows zero. tshl[t][0..31] = (hi,lo) bf16 split of tsq+BIAS (large-finite
// for pads), tshl[t][32..63] = 0 (zero source for hi=1 lanes). tsqe = exact |t|^2.
__global__ void prep_kernel(const float* __restrict__ tgt, unsigned short* __restrict__ tbf,
                            unsigned* __restrict__ tshl, float* __restrict__ tsqe,
                            int M, int Mpad) {
    int row  = blockIdx.x;
    int lane = threadIdx.x;  // 64
    if (row >= Mpad) return;
    float2 v = make_float2(0.f, 0.f);
    if (row < M) v = *(const float2*)(tgt + (size_t)row * D + lane * 2);
    unsigned pack = (unsigned)f2bf(-2.f * v.x) | ((unsigned)f2bf(-2.f * v.y) << 16);
    size_t byte = (size_t)row * 256 + (size_t)(((lane >> 2) ^ (row & 15)) * 16 + (lane & 3) * 4);
    *(unsigned*)((char*)tbf + byte) = pack;
    float ss = v.x * v.x + v.y * v.y;
    #pragma unroll
    for (int off = 1; off < 64; off <<= 1) ss += __shfl_xor(ss, off);
    if (lane == 0) {
        tsqe[row] = ss;
        float pv = (row < M) ? (ss + BIAS) : 1e30f;
        unsigned hv = f2bf(pv);
        float hf = __uint_as_float(hv << 16);
        unsigned lv = f2bf(pv - hf);
        int t = row >> 5, r = row & 31;
        tshl[t * 64 + r]      = hv | (lv << 16);
        tshl[t * 64 + 32 + r] = 0;
    }
}

// Scan: 32x32x16-bf16 MFMA core (9 MFMA per 1024 distances: 1 tsq-fold + 8 K-slices).
// Per thread TWO depth-5 chains (C-regs 0-7 / 8-15) -> 40 keys/source (validated).
// Triple-buffered counted-vmcnt protocol. __launch_bounds__(256,6): 6 blocks/CU
// resident (grid is 6.1/CU, LDS 25.3KB allows 6) — r14 capped at 4 with (256,4);
// VGPR budget 84 >= r14's 48 so no spill expected (canary: FETCH_SIZE).
__global__ __launch_bounds__(256, 6)
void knn_scan(const float* __restrict__ src, const unsigned short* __restrict__ tbf,
              const unsigned* __restrict__ tshl, unsigned* __restrict__ keys,
              int N, int M, int h0, int msteps) {
    const int tid  = (int)threadIdx.x;
    const int wid  = tid >> 6;
    const int lane = tid & 63;
    const int col  = lane & 31;   // B col (source) and A row (target)
    const int hi   = lane >> 5;   // k-half
    const int half = blockIdx.y;
    const int colbase = blockIdx.x * (WAVES * 32) + wid * 32;
    const int srow = colbase + col;
    const int srcl = srow < N ? srow : (N - 1);

    __shared__ __align__(16) char smem[3 * BUFB];   // 25344 B

    // ---- B fragments: source srcl, k = 16m + 8*hi + e
    short8 bfrag[8];
    {
        const float* sp = src + (size_t)srcl * D + hi * 8;
        #pragma unroll
        for (int m = 0; m < 8; ++m) {
            float4 v0 = *(const float4*)(sp + m * 16);
            float4 v1 = *(const float4*)(sp + m * 16 + 4);
            short8 b;
            b[0] = (short)f2bf(v0.x); b[1] = (short)f2bf(v0.y);
            b[2] = (short)f2bf(v0.z); b[3] = (short)f2bf(v0.w);
            b[4] = (short)f2bf(v1.x); b[5] = (short)f2bf(v1.y);
            b[6] = (short)f2bf(v1.z); b[7] = (short)f2bf(v1.w);
            bfrag[m] = b;
        }
    }

    // b2: ones at slots (hi=0, e=0,1) pairing with tshl hi/lo; zero for hi=1
    U8 b2u; b2u.u[0] = hi ? 0u : 0x3F803F80u; b2u.u[1] = 0; b2u.u[2] = 0; b2u.u[3] = 0;

    f32x16 zz;
    #pragma unroll
    for (int e = 0; e < 16; ++e) zz[e] = 0.f;

    // A-read byte offsets (swizzled): elems k=16m+8hi of row `col`
    int aoff[8];
    #pragma unroll
    for (int m = 0; m < 8; ++m) aoff[m] = col * 256 + (((2 * m + hi) ^ (col & 15)) * 16);
    const int toff = TILEB + col * 4 + hi * 128;   // hi=1 lanes read zeros

    unsigned stA[5], stB[5];
    #pragma unroll
    for (int s = 0; s < 5; ++s) { stA[s] = 0xFFFFFFFFu; stB[s] = 0xFFFFFFFFu; }
    const unsigned hib = (unsigned)(hi << 4);

    const int t0 = half ? h0 : 0;
    const int tc = half ? (msteps - h0) : h0;   // %3 == 0 by padding
    const int tlast = t0 + tc - 1;

    #define STAGE(tile, b)                                                          \
        do {                                                                        \
            const char* gb_ = (const char*)tbf + (size_t)(tile) * TILEB;            \
            char* lb_ = smem + (size_t)(b) * BUFB;                                  \
            gload_lds16(gb_ + wid * 2048 + lane * 16, lb_ + wid * 2048);            \
            gload_lds16(gb_ + wid * 2048 + 1024 + lane * 16, lb_ + wid * 2048 + 1024);\
            gload_lds4((const char*)tshl + (size_t)(tile) * 256 + lane * 4,         \
                       lb_ + TILEB);                                                \
        } while (0)

    #define COMPUTE(b, tile)                                                        \
        do {                                                                        \
            const char* base_ = smem + (size_t)(b) * BUFB;                          \
            unsigned pair_ = *(const unsigned*)(base_ + toff);                      \
            U8 a2u_; a2u_.u[0] = pair_; a2u_.u[1] = 0; a2u_.u[2] = 0; a2u_.u[3] = 0;\
            f32x16 acc = __builtin_amdgcn_mfma_f32_32x32x16_bf16(a2u_.s, b2u.s, zz, 0, 0, 0);\
            _Pragma("unroll")                                                       \
            for (int m = 0; m < 8; ++m) {                                           \
                short8 am_ = *(const short8*)(base_ + aoff[m]);                     \
                acc = __builtin_amdgcn_mfma_f32_32x32x16_bf16(am_, bfrag[m], acc, 0, 0, 0);\
            }                                                                       \
            unsigned vb_ = ((unsigned)(tile) << 5) | hib;                           \
            _Pragma("unroll")                                                       \
            for (int r = 0; r < 8; ++r) {                                           \
                unsigned key_ = (__float_as_uint(acc[r]) & 0xFFFFE000u) | vb_ | (unsigned)r;\
                ins5(stA, key_);                                                    \
            }                                                                       \
            _Pragma("unroll")                                                       \
            for (int r = 8; r < 16; ++r) {                                          \
                unsigned key_ = (__float_as_uint(acc[r]) & 0xFFFFE000u) | vb_ | (unsigned)r;\
                ins5(stB, key_);                                                    \
            }                                                                       \
        } while (0)

    STAGE(t0, 0);
    STAGE(t0 + 1, 1);
    asm volatile("s_waitcnt vmcnt(3)\n\ts_barrier" ::: "memory");   // tile t0 ready

    for (int i = 0; i < tc; i += 3) {
        int t_ = t0 + i;
        int s2 = t_ + 2 < tlast ? t_ + 2 : tlast;
        int s3 = t_ + 3 < tlast ? t_ + 3 : tlast;
        int s4 = t_ + 4 < tlast ? t_ + 4 : tlast;
        STAGE(s2, 2);
        COMPUTE(0, t_);
        asm volatile("s_waitcnt vmcnt(3)\n\ts_barrier" ::: "memory");
        STAGE(s3, 0);
        COMPUTE(1, t_ + 1);
        asm volatile("s_waitcnt vmcnt(3)\n\ts_barrier" ::: "memory");
        STAGE(s4, 1);
        COMPUTE(2, t_ + 2);
        asm volatile("s_waitcnt vmcnt(3)\n\ts_barrier" ::: "memory");
    }
    asm volatile("s_waitcnt vmcnt(0)" ::: "memory");
    #undef STAGE
    #undef COMPUTE

    if (srow < N) {
        unsigned* kp = keys + (size_t)srow * 40 + half * 20 + hi * 10;
        #pragma unroll
        for (int s = 0; s < 5; ++s) { kp[s] = stA[s]; kp[5 + s] = stB[s]; }
    }
}

// Merge: 1 thread per source. Top-10 (by truncated bf16 key) of the 40
// candidates, decode, exact fp32 refine of those 10, top-3 + softmax + output.
__global__ __launch_bounds__(256, 4)
void knn_merge(const float* __restrict__ src, const float* __restrict__ tgt,
               const float* __restrict__ tsqe, const unsigned* __restrict__ keys,
               const float* __restrict__ tpts, float* __restrict__ out,
               int N, int M) {
    int i = blockIdx.x * 256 + (int)threadIdx.x;
    if (i >= N) return;

    unsigned best[REFK];
    #pragma unroll
    for (int s = 0; s < REFK; ++s) best[s] = 0xFFFFFFFFu;

    const uint4* kp = (const uint4*)(keys + (size_t)i * 40);
    #pragma unroll
    for (int q = 0; q < 10; ++q) {
        uint4 kv = kp[q];
        ins10(best, kv.x); ins10(best, kv.y); ins10(best, kv.z); ins10(best, kv.w);
    }

    int js[REFK]; float dt[REFK];
    #pragma unroll
    for (int s = 0; s < REFK; ++s) {
        unsigned idx = best[s] & 0x1FFFu;
        int tile = (int)(idx >> 5);
        int hh   = (int)((idx >> 4) & 1u);
        int reg  = (int)(idx & 15u);
        int row  = tile * 32 + (reg & 3) + 8 * (reg >> 2) + 4 * hh;
        js[s] = (row < M) ? row : (M - 1);
        dt[s] = 0.f;
    }

    const float4* sp = (const float4*)(src + (size_t)i * D);
    for (int kc = 0; kc < D / 4; ++kc) {
        float4 sv = sp[kc];
        #pragma unroll
        for (int s = 0; s < REFK; ++s) {
            float4 tv = *(const float4*)(tgt + (size_t)js[s] * D + kc * 4);
            dt[s] = fmaf(sv.x, tv.x, fmaf(sv.y, tv.y, fmaf(sv.z, tv.z, fmaf(sv.w, tv.w, dt[s]))));
        }
    }

    float d0 = __builtin_inff(), d1 = d0, d2 = d0;
    int i0 = 0, i1 = 0, i2 = 0;
    #pragma unroll
    for (int s = 0; s < REFK; ++s) {
        float dd = fmaf(-2.f, dt[s], tsqe[js[s]]);
        int jj = js[s];
        if (dd < d2) {
            if (dd < d1) {
                d2 = d1; i2 = i1;
                if (dd < d0) { d1 = d0; i1 = i0; d0 = dd; i0 = jj; }
                else         { d1 = dd; i1 = jj; }
            } else { d2 = dd; i2 = jj; }
        }
    }

    float e1 = __expf(d0 - d1);
    float e2 = __expf(d0 - d2);
    float inv = 1.f / (1.f + e1 + e2);
    float w0 = inv, w1 = e1 * inv, w2 = e2 * inv;
    const float* p0 = tpts + 3 * (size_t)i0;
    const float* p1 = tpts + 3 * (size_t)i1;
    const float* p2 = tpts + 3 * (size_t)i2;
    out[3 * (size_t)i + 0] = w0 * p0[0] + w1 * p1[0] + w2 * p2[0];
    out[3 * (size_t)i + 1] = w0 * p0[1] + w1 * p1[1] + w2 * p2[1];
    out[3 * (size_t)i + 2] = w0 * p0[2] + w1 * p1[2] + w2 * p2[2];
}

extern "C" void kernel_launch(void* const* d_in, const int* in_sizes, int n_in,
                              void* d_out, int out_size, void* d_ws, size_t ws_size,
                              hipStream_t stream) {
    const float* src  = (const float*)d_in[0];  // [N,128]
    const float* tgt  = (const float*)d_in[1];  // [M,128]
    const float* tpts = (const float*)d_in[2];  // [M,3]
    float* out = (float*)d_out;

    int N = in_sizes[0] / D;
    int M = in_sizes[1] / D;
    int Mpad = (M + 191) & ~191;                // 6912; msteps % 6 == 0
    int msteps = Mpad >> 5;                     // 216
    int h0 = msteps >> 1;                       // 108 (div by 3)

    // ws: tbf (Mpad*256, swizzled) | tshl (msteps*256) | tsqe (Mpad*4) | keys (N*40*4)
    char* w = (char*)d_ws;
    unsigned short* tbf = (unsigned short*)w;                 w += (size_t)Mpad * 256;
    unsigned* tshl = (unsigned*)w;                            w += (size_t)msteps * 256;
    float* tsqe = (float*)w;                                  w += (size_t)Mpad * 4;
    unsigned* keys = (unsigned*)w;

    prep_kernel<<<Mpad, 64, 0, stream>>>(tgt, tbf, tshl, tsqe, M, Mpad);

    dim3 sgrid((N + 127) / 128, 2);             // 782 x 2
    knn_scan<<<sgrid, 256, 0, stream>>>(src, tbf, tshl, keys, N, M, h0, msteps);

    knn_merge<<<(N + 255) / 256, 256, 0, stream>>>(src, tgt, tsqe, keys, tpts, out, N, M);
}

// Round 17
// 341.303 us; speedup vs baseline: 1.5079x; 1.5079x over previous
//
#include <hip/hip_runtime.h>
#include <math.h>

#define D 128
#define WAVES 4                    // waves per block; block covers 128 sources
#define BIAS 16.0f
#define TILEB 8192                 // 32-row A-tile bytes
#define BUFB  8448                 // tile + 256B tshl slot

typedef __attribute__((ext_vector_type(8))) short short8;    // 8 bf16
typedef __attribute__((ext_vector_type(16))) float f32x16;   // 32x32 acc

union U8 { short8 s; unsigned u[4]; };

// fp32 -> bf16 bits, round-to-nearest-even
static __device__ __forceinline__ unsigned short f2bf(float x) {
    unsigned u = __float_as_uint(x);
    unsigned r = u + 0x7FFFu + ((u >> 16) & 1u);
    return (unsigned short)(r >> 16);
}

static __device__ __forceinline__ unsigned med3u(unsigned a, unsigned b, unsigned c) {
    unsigned d;
    asm("v_med3_u32 %0, %1, %2, %3" : "=v"(d) : "v"(a), "v"(b), "v"(c));
    return d;
}

// exact sorted-ascending top-5 insert: 4 med3 + 1 min (validated r6-r14)
static __device__ __forceinline__ void ins5(unsigned st[5], unsigned k) {
    st[4] = med3u(st[4], st[3], k);
    st[3] = med3u(st[3], st[2], k);
    st[2] = med3u(st[2], st[1], k);
    st[1] = med3u(st[1], st[0], k);
    st[0] = st[0] < k ? st[0] : k;
}

static __device__ __forceinline__ unsigned umn(unsigned x, unsigned y) { return x < y ? x : y; }
static __device__ __forceinline__ unsigned umx(unsigned x, unsigned y) { return x > y ? x : y; }

// merge two ascending 5-lists -> ascending 5 smallest of union:
// c[k] = min(a[k], b[k], min_{i+j=k-1} max(a[i], b[j]))
static __device__ __forceinline__ void merge5(const unsigned a[5], const unsigned b[5], unsigned c[5]) {
    c[0] = umn(a[0], b[0]);
    c[1] = umn(umn(a[1], b[1]), umx(a[0], b[0]));
    c[2] = umn(umn(a[2], b[2]), umn(umx(a[1], b[0]), umx(a[0], b[1])));
    c[3] = umn(umn(a[3], b[3]), umn(umx(a[2], b[0]), umn(umx(a[1], b[1]), umx(a[0], b[2]))));
    c[4] = umn(umn(a[4], b[4]), umn(umn(umx(a[3], b[0]), umx(a[2], b[1])),
                                    umn(umx(a[1], b[2]), umx(a[0], b[3]))));
}

static __device__ __forceinline__ void gload_lds16(const void* g, void* l) {
    __builtin_amdgcn_global_load_lds(
        (const __attribute__((address_space(1))) unsigned*)g,
        (__attribute__((address_space(3))) unsigned*)l, 16, 0, 0);
}
static __device__ __forceinline__ void gload_lds4(const void* g, void* l) {
    __builtin_amdgcn_global_load_lds(
        (const __attribute__((address_space(1))) unsigned*)g,
        (__attribute__((address_space(3))) unsigned*)l, 4, 0, 0);
}

// Phase 0: tbf = bf16(-2*tgt), PRE-SWIZZLED (16B-unit u of row r at u^(r&15));
// pad rows zero. tshl[t][0..31] = (hi,lo) bf16 split of tsq+BIAS (large-finite
// for pads), tshl[t][32..63] = 0. tsqe = exact |t|^2.
__global__ void prep_kernel(const float* __restrict__ tgt, unsigned short* __restrict__ tbf,
                            unsigned* __restrict__ tshl, float* __restrict__ tsqe,
                            int M, int Mpad) {
    int row  = blockIdx.x;
    int lane = threadIdx.x;  // 64
    if (row >= Mpad) return;
    float2 v = make_float2(0.f, 0.f);
    if (row < M) v = *(const float2*)(tgt + (size_t)row * D + lane * 2);
    unsigned pack = (unsigned)f2bf(-2.f * v.x) | ((unsigned)f2bf(-2.f * v.y) << 16);
    size_t byte = (size_t)row * 256 + (size_t)(((lane >> 2) ^ (row & 15)) * 16 + (lane & 3) * 4);
    *(unsigned*)((char*)tbf + byte) = pack;
    float ss = v.x * v.x + v.y * v.y;
    #pragma unroll
    for (int off = 1; off < 64; off <<= 1) ss += __shfl_xor(ss, off);
    if (lane == 0) {
        tsqe[row] = ss;
        float pv = (row < M) ? (ss + BIAS) : 1e30f;
        unsigned hv = f2bf(pv);
        float hf = __uint_as_float(hv << 16);
        unsigned lv = f2bf(pv - hf);
        int t = row >> 5, r = row & 31;
        tshl[t * 64 + r]      = hv | (lv << 16);
        tshl[t * 64 + 32 + r] = 0;
    }
}

// Scan: r14 core (validated): 32x32x16 MFMA, 9 MFMA/tile, two depth-5 chains
// per thread, triple-buffered counted-vmcnt, (256,4). Epilogue: lane-local
// merge5(stA,stB) -> cross-hi shfl merge5 -> 5 keys per (source,half).
__global__ __launch_bounds__(256, 4)
void knn_scan(const float* __restrict__ src, const unsigned short* __restrict__ tbf,
              const unsigned* __restrict__ tshl, unsigned* __restrict__ keys,
              int N, int M, int h0, int msteps) {
    const int tid  = (int)threadIdx.x;
    const int wid  = tid >> 6;
    const int lane = tid & 63;
    const int col  = lane & 31;   // B col (source) and A row (target)
    const int hi   = lane >> 5;   // k-half
    const int half = blockIdx.y;
    const int colbase = blockIdx.x * (WAVES * 32) + wid * 32;
    const int srow = colbase + col;
    const int srcl = srow < N ? srow : (N - 1);

    __shared__ __align__(16) char smem[3 * BUFB];   // 25344 B

    // ---- B fragments: source srcl, k = 16m + 8*hi + e
    short8 bfrag[8];
    {
        const float* sp = src + (size_t)srcl * D + hi * 8;
        #pragma unroll
        for (int m = 0; m < 8; ++m) {
            float4 v0 = *(const float4*)(sp + m * 16);
            float4 v1 = *(const float4*)(sp + m * 16 + 4);
            short8 b;
            b[0] = (short)f2bf(v0.x); b[1] = (short)f2bf(v0.y);
            b[2] = (short)f2bf(v0.z); b[3] = (short)f2bf(v0.w);
            b[4] = (short)f2bf(v1.x); b[5] = (short)f2bf(v1.y);
            b[6] = (short)f2bf(v1.z); b[7] = (short)f2bf(v1.w);
            bfrag[m] = b;
        }
    }

    // b2: ones at slots (hi=0, e=0,1) pairing with tshl hi/lo; zero for hi=1
    U8 b2u; b2u.u[0] = hi ? 0u : 0x3F803F80u; b2u.u[1] = 0; b2u.u[2] = 0; b2u.u[3] = 0;

    f32x16 zz;
    #pragma unroll
    for (int e = 0; e < 16; ++e) zz[e] = 0.f;

    // A-read byte offsets (swizzled): elems k=16m+8hi of row `col`
    int aoff[8];
    #pragma unroll
    for (int m = 0; m < 8; ++m) aoff[m] = col * 256 + (((2 * m + hi) ^ (col & 15)) * 16);
    const int toff = TILEB + col * 4 + hi * 128;   // hi=1 lanes read zeros

    unsigned stA[5], stB[5];
    #pragma unroll
    for (int s = 0; s < 5; ++s) { stA[s] = 0xFFFFFFFFu; stB[s] = 0xFFFFFFFFu; }
    const unsigned hib = (unsigned)(hi << 4);

    const int t0 = half ? h0 : 0;
    const int tc = half ? (msteps - h0) : h0;   // %3 == 0 by padding
    const int tlast = t0 + tc - 1;

    #define STAGE(tile, b)                                                          \
        do {                                                                        \
            const char* gb_ = (const char*)tbf + (size_t)(tile) * TILEB;            \
            char* lb_ = smem + (size_t)(b) * BUFB;                                  \
            gload_lds16(gb_ + wid * 2048 + lane * 16, lb_ + wid * 2048);            \
            gload_lds16(gb_ + wid * 2048 + 1024 + lane * 16, lb_ + wid * 2048 + 1024);\
            gload_lds4((const char*)tshl + (size_t)(tile) * 256 + lane * 4,         \
                       lb_ + TILEB);                                                \
        } while (0)

    #define COMPUTE(b, tile)                                                        \
        do {                                                                        \
            const char* base_ = smem + (size_t)(b) * BUFB;                          \
            unsigned pair_ = *(const unsigned*)(base_ + toff);                      \
            U8 a2u_; a2u_.u[0] = pair_; a2u_.u[1] = 0; a2u_.u[2] = 0; a2u_.u[3] = 0;\
            f32x16 acc = __builtin_amdgcn_mfma_f32_32x32x16_bf16(a2u_.s, b2u.s, zz, 0, 0, 0);\
            _Pragma("unroll")                                                       \
            for (int m = 0; m < 8; ++m) {                                           \
                short8 am_ = *(const short8*)(base_ + aoff[m]);                     \
                acc = __builtin_amdgcn_mfma_f32_32x32x16_bf16(am_, bfrag[m], acc, 0, 0, 0);\
            }                                                                       \
            unsigned vb_ = ((unsigned)(tile) << 5) | hib;                           \
            _Pragma("unroll")                                                       \
            for (int r = 0; r < 8; ++r) {                                           \
                unsigned key_ = (__float_as_uint(acc[r]) & 0xFFFFE000u) | vb_ | (unsigned)r;\
                ins5(stA, key_);                                                    \
            }                                                                       \
            _Pragma("unroll")                                                       \
            for (int r = 8; r < 16; ++r) {                                          \
                unsigned key_ = (__float_as_uint(acc[r]) & 0xFFFFE000u) | vb_ | (unsigned)r;\
                ins5(stB, key_);                                                    \
            }                                                                       \
        } while (0)

    STAGE(t0, 0);
    STAGE(t0 + 1, 1);
    asm volatile("s_waitcnt vmcnt(3)\n\ts_barrier" ::: "memory");   // tile t0 ready

    for (int i = 0; i < tc; i += 3) {
        int t_ = t0 + i;
        int s2 = t_ + 2 < tlast ? t_ + 2 : tlast;
        int s3 = t_ + 3 < tlast ? t_ + 3 : tlast;
        int s4 = t_ + 4 < tlast ? t_ + 4 : tlast;
        STAGE(s2, 2);
        COMPUTE(0, t_);
        asm volatile("s_waitcnt vmcnt(3)\n\ts_barrier" ::: "memory");
        STAGE(s3, 0);
        COMPUTE(1, t_ + 1);
        asm volatile("s_waitcnt vmcnt(3)\n\ts_barrier" ::: "memory");
        STAGE(s4, 1);
        COMPUTE(2, t_ + 2);
        asm volatile("s_waitcnt vmcnt(3)\n\ts_barrier" ::: "memory");
    }
    asm volatile("s_waitcnt vmcnt(0)" ::: "memory");
    #undef STAGE
    #undef COMPUTE

    // ---- epilogue: 20 keys (2 chains x 2 hi) -> top-5 for (source,half) ----
    unsigned m5[5], o5[5], f5[5];
    merge5(stA, stB, m5);                       // lane-local top-5 of 10
    #pragma unroll
    for (int s = 0; s < 5; ++s) o5[s] = __shfl_xor(m5[s], 32);   // hi-partner's
    merge5(m5, o5, f5);                         // top-5 of this half's 20

    if (srow < N && hi == 0) {
        unsigned* kp = keys + (size_t)srow * 10 + half * 5;
        #pragma unroll
        for (int s = 0; s < 5; ++s) kp[s] = f5[s];
    }
}

// Merge: ONE WAVE per source. 8 lanes per candidate (cands 0-7 pass A, 8-9
// pass B): coalesced reads, 16-FMA partial dot, shfl_xor reduce. Candidate
// collection shuffles run with ALL lanes active (r16 bug: they were inside the
// lane-0 branch -> inactive source lanes -> undefined values).
__global__ __launch_bounds__(256, 8)
void knn_merge(const float* __restrict__ src, const float* __restrict__ tgt,
               const float* __restrict__ tsqe, const unsigned* __restrict__ keys,
               const float* __restrict__ tpts, float* __restrict__ out,
               int N, int M) {
    const int wv   = blockIdx.x * 4 + ((int)threadIdx.x >> 6);   // source
    const int lane = (int)threadIdx.x & 63;
    if (wv >= N) return;   // N % 4 == 0 -> whole wave uniform
    const int seg = lane & 7;    // 16-float segment within row

    unsigned k10 = 0xFFFFFFFFu;
    if (lane < 10) k10 = keys[(size_t)wv * 10 + lane];

    // src segment (16 floats)
    const float4* spv = (const float4*)(src + (size_t)wv * D + seg * 16);
    float4 s0 = spv[0], s1 = spv[1], s2 = spv[2], s3 = spv[3];

    #define DECODE(kk, rr)                                                   \
        do {                                                                 \
            unsigned idx_ = (kk) & 0x1FFFu;                                  \
            int reg_ = (int)(idx_ & 15u);                                    \
            int row_ = (int)(idx_ >> 5) * 32 + (reg_ & 3) + 8 * (reg_ >> 2)  \
                       + 4 * (int)((idx_ >> 4) & 1u);                        \
            (rr) = row_ < M ? row_ : (M - 1);                                \
        } while (0)

    #define DOT16(rr, dd)                                                    \
        do {                                                                 \
            const float4* tp_ = (const float4*)(tgt + (size_t)(rr) * D + seg * 16);\
            float4 t0 = tp_[0], t1 = tp_[1], t2 = tp_[2], t3 = tp_[3];       \
            float d_ = 0.f;                                                  \
            d_ = fmaf(s0.x, t0.x, d_); d_ = fmaf(s0.y, t0.y, d_);            \
            d_ = fmaf(s0.z, t0.z, d_); d_ = fmaf(s0.w, t0.w, d_);            \
            d_ = fmaf(s1.x, t1.x, d_); d_ = fmaf(s1.y, t1.y, d_);            \
            d_ = fmaf(s1.z, t1.z, d_); d_ = fmaf(s1.w, t1.w, d_);            \
            d_ = fmaf(s2.x, t2.x, d_); d_ = fmaf(s2.y, t2.y, d_);            \
            d_ = fmaf(s2.z, t2.z, d_); d_ = fmaf(s2.w, t2.w, d_);            \
            d_ = fmaf(s3.x, t3.x, d_); d_ = fmaf(s3.y, t3.y, d_);            \
            d_ = fmaf(s3.z, t3.z, d_); d_ = fmaf(s3.w, t3.w, d_);            \
            d_ += __shfl_xor(d_, 1); d_ += __shfl_xor(d_, 2); d_ += __shfl_xor(d_, 4);\
            (dd) = d_;                                                       \
        } while (0)

    // pass A: cand = lane>>3
    unsigned kA = __shfl(k10, lane >> 3);
    int rowA; DECODE(kA, rowA);
    float dA; DOT16(rowA, dA);
    float cdA = fmaf(-2.f, dA, tsqe[rowA]);

    // pass B: cands 8,9
    unsigned kB = __shfl(k10, 8 + ((lane >> 3) & 1));
    int rowB; DECODE(kB, rowB);
    float dB; DOT16(rowB, dB);
    float cdB = fmaf(-2.f, dB, tsqe[rowB]);
    #undef DECODE
    #undef DOT16

    // ---- collect all 10 (ALL lanes active: defined shuffle behavior) ----
    float cds[10]; int rows[10];
    #pragma unroll
    for (int c = 0; c < 8; ++c) {
        cds[c]  = __shfl(cdA,  c * 8);
        rows[c] = __shfl(rowA, c * 8);
    }
    cds[8] = __shfl(cdB, 0);  rows[8] = __shfl(rowB, 0);
    cds[9] = __shfl(cdB, 8);  rows[9] = __shfl(rowB, 8);

    if (lane == 0) {
        float d0 = __builtin_inff(), d1 = d0, d2 = d0;
        int i0 = 0, i1 = 0, i2 = 0;
        #pragma unroll
        for (int s = 0; s < 10; ++s) {
            float dd = cds[s]; int jj = rows[s];
            if (dd < d2) {
                if (dd < d1) {
                    d2 = d1; i2 = i1;
                    if (dd < d0) { d1 = d0; i1 = i0; d0 = dd; i0 = jj; }
                    else         { d1 = dd; i1 = jj; }
                } else { d2 = dd; i2 = jj; }
            }
        }
        float e1 = __expf(d0 - d1);
        float e2 = __expf(d0 - d2);
        float inv = 1.f / (1.f + e1 + e2);
        float w0 = inv, w1 = e1 * inv, w2 = e2 * inv;
        const float* p0 = tpts + 3 * (size_t)i0;
        const float* p1 = tpts + 3 * (size_t)i1;
        const float* p2 = tpts + 3 * (size_t)i2;
        out[3 * (size_t)wv + 0] = w0 * p0[0] + w1 * p1[0] + w2 * p2[0];
        out[3 * (size_t)wv + 1] = w0 * p0[1] + w1 * p1[1] + w2 * p2[1];
        out[3 * (size_t)wv + 2] = w0 * p0[2] + w1 * p1[2] + w2 * p2[2];
    }
}

extern "C" void kernel_launch(void* const* d_in, const int* in_sizes, int n_in,
                              void* d_out, int out_size, void* d_ws, size_t ws_size,
                              hipStream_t stream) {
    const float* src  = (const float*)d_in[0];  // [N,128]
    const float* tgt  = (const float*)d_in[1];  // [M,128]
    const float* tpts = (const float*)d_in[2];  // [M,3]
    float* out = (float*)d_out;

    int N = in_sizes[0] / D;
    int M = in_sizes[1] / D;
    int Mpad = (M + 191) & ~191;                // 6912; msteps % 6 == 0
    int msteps = Mpad >> 5;                     // 216
    int h0 = msteps >> 1;                       // 108 (div by 3)

    // ws: tbf (Mpad*256, swizzled) | tshl (msteps*256) | tsqe (Mpad*4) | keys (N*10*4)
    char* w = (char*)d_ws;
    unsigned short* tbf = (unsigned short*)w;                 w += (size_t)Mpad * 256;
    unsigned* tshl = (unsigned*)w;                            w += (size_t)msteps * 256;
    float* tsqe = (float*)w;                                  w += (size_t)Mpad * 4;
    unsigned* keys = (unsigned*)w;

    prep_kernel<<<Mpad, 64, 0, stream>>>(tgt, tbf, tshl, tsqe, M, Mpad);

    dim3 sgrid((N + 127) / 128, 2);             // 782 x 2
    knn_scan<<<sgrid, 256, 0, stream>>>(src, tbf, tshl, keys, N, M, h0, msteps);

    knn_merge<<<(N + 3) / 4, 256, 0, stream>>>(src, tgt, tsqe, keys, tpts, out, N, M);
}